// Round 2
// baseline (266.810 us; speedup 1.0000x reference)
//
#include <hip/hip_runtime.h>

// Problem constants (from reference setup_inputs): B=16, R=1, A=16, T=14, S=1024
static constexpr int kB = 16;
static constexpr int kA = 16;
static constexpr int kT = 14;
static constexpr int kS = 1024;
static constexpr int kMaxMatch = 32;

// native clang vector (required by __builtin_nontemporal_store)
typedef __attribute__((ext_vector_type(4))) float fvec4;

// y layout: (B, R=1, A, T, S) float32 contiguous.
// Output (complex path, the one used): (B, R=1, T, S, A, A) complex64 interleaved.
// Row layout per (b,t,s): 256 complex = 512 floats = 128 float4; float4 slot q
// holds complex elems (2q, 2q+1) = (i = q>>3, j = (q&7)*2 and +1).

// ==========================================================================
// FAST PATH Kernel A: compute cov into workspace ws4[((b<<10)+s)*128 + q].
// One block per (b,s), 128 threads. Same math as the verified cplx kernel,
// but writes 2 KB instead of 28 KB -> 33.5 MB total.
// ==========================================================================
__global__ __launch_bounds__(128) void cov_compute_ws(
    const float* __restrict__ y_real,
    const float* __restrict__ y_imag,
    const int*   __restrict__ est,      // (P,2): [sym, sc] int32 (sniffs int64 too)
    const int*   __restrict__ closest,  // (S,)  int32 (sniffs int64 too)
    fvec4*       __restrict__ ws4,
    int P)
{
    const int blk = blockIdx.x;          // = (b<<10) + s
    const int b   = blk >> 10;
    const int s   = blk & (kS - 1);
    const int tid = threadIdx.x;

    // layout sniff: int64 arrays of small values have all-zero odd words
    bool est64 = true;
    {
        int lim = 2 * P; if (lim > 128) lim = 128;
        for (int k = 1; k < lim; k += 2)
            if (est[k] != 0) { est64 = false; break; }
    }
    bool clo64 = true;
    {
        int lim = kS; if (lim > 128) lim = 128;
        for (int k = 1; k < lim; k += 2)
            if (closest[k] != 0) { clo64 = false; break; }
    }

    int c = closest[clo64 ? 2 * s : s];
    if (c < 0) c = 0;
    if (c >= kS) c = kS - 1;

    __shared__ int   sm_count;
    __shared__ int   sm_sym[kMaxMatch];
    __shared__ float sm_re[kA], sm_im[kA];

    if (tid == 0) sm_count = 0;
    __syncthreads();

    for (int p = tid; p < P; p += 128) {
        const int sc = est[est64 ? 4 * p + 2 : 2 * p + 1];
        if (sc == c) {
            const int sym = est[est64 ? 4 * p : 2 * p];
            if (sym >= 0 && sym < kT) {
                int slot = atomicAdd(&sm_count, 1);
                if (slot < kMaxMatch) sm_sym[slot] = sym;
            }
        }
    }
    __syncthreads();

    int count = sm_count;
    if (count > kMaxMatch) count = kMaxMatch;

    const int i  = tid >> 3;          // 0..15
    const int j0 = (tid & 7) * 2;     // 0,2,..,14

    float a0r = 0.f, a0i = 0.f, a1r = 0.f, a1i = 0.f;

    for (int m = 0; m < count; ++m) {
        const int sym = sm_sym[m];
        if (tid < kA) {
            const long off = (long)b * (kA * kT * kS) + (long)tid * (kT * kS)
                           + (long)sym * kS + c;
            sm_re[tid] = y_real[off];
            sm_im[tid] = y_imag[off];
        }
        __syncthreads();

        const float xr  = sm_re[i],      xi  = sm_im[i];
        const float y0r = sm_re[j0],     y0i = sm_im[j0];
        const float y1r = sm_re[j0 + 1], y1i = sm_im[j0 + 1];
        a0r += xr * y0r + xi * y0i;
        a0i += xi * y0r - xr * y0i;
        a1r += xr * y1r + xi * y1i;
        a1i += xi * y1r - xr * y1i;
        __syncthreads();
    }

    const float inv = 1.0f / (float)(count > 0 ? count : 1);
    fvec4 v; v.x = a0r * inv; v.y = a0i * inv; v.z = a1r * inv; v.w = a1i * inv;
    ws4[(long)blk * 128 + tid] = v;
}

// ==========================================================================
// FAST PATH Kernel B: pure broadcast ws -> out. Block owns (b, 8 subcarriers):
// reads 1024 float4 (16 KB) into registers (4/thread), then writes the same
// 16 KB contiguous chunk for each of the 14 symbols, nontemporal. This is
// structurally a fill with a register pattern -> expect fill-rate BW.
// ==========================================================================
__global__ __launch_bounds__(256) void cov_broadcast(
    const fvec4* __restrict__ ws4,
    fvec4*       __restrict__ out4,
    long out_floats)                 // same guard semantics as verified kernel
{
    const int b     = blockIdx.x >> 7;        // kS/8 = 128 chunks per b
    const int chunk = blockIdx.x & 127;
    const int s0    = chunk << 3;             // 8 s-rows per block
    const int tid   = threadIdx.x;

    const fvec4* __restrict__ src = ws4 + ((long)((b << 10) + s0)) * 128;
    const fvec4 r0 = src[tid];
    const fvec4 r1 = src[tid + 256];
    const fvec4 r2 = src[tid + 512];
    const fvec4 r3 = src[tid + 768];

    #pragma unroll
    for (int t = 0; t < kT; ++t) {
        const long base = ((long)((b * kT + t) << 10) + s0) * 128;
        // uniform fast-path check (scalar branch); guard: (idx+1)*4 <= out_floats
        if ((base + 1024) * 4 <= out_floats) {
            __builtin_nontemporal_store(r0, out4 + base + tid);
            __builtin_nontemporal_store(r1, out4 + base + tid + 256);
            __builtin_nontemporal_store(r2, out4 + base + tid + 512);
            __builtin_nontemporal_store(r3, out4 + base + tid + 768);
        } else {
            if ((base + tid + 1)       * 4 <= out_floats) out4[base + tid]       = r0;
            if ((base + tid + 256 + 1) * 4 <= out_floats) out4[base + tid + 256] = r1;
            if ((base + tid + 512 + 1) * 4 <= out_floats) out4[base + tid + 512] = r2;
            if ((base + tid + 768 + 1) * 4 <= out_floats) out4[base + tid + 768] = r3;
        }
    }
}

// ==========================================================================
// FALLBACK kernels (verbatim from verified session) — used if ws too small
// or the real-output branch is taken.
// ==========================================================================
__global__ __launch_bounds__(64) void cov_real_kernel(
    const float* __restrict__ y_real,
    const float* __restrict__ y_imag,
    const int*   __restrict__ est,
    const int*   __restrict__ closest,
    float*       __restrict__ out,
    int P, long out_floats)
{
    const int blk = blockIdx.x;
    const int b   = blk >> 10;
    const int s   = blk & (kS - 1);
    const int tid = threadIdx.x;

    bool est64 = true;
    {
        int lim = 2 * P; if (lim > 128) lim = 128;
        for (int k = 1; k < lim; k += 2)
            if (est[k] != 0) { est64 = false; break; }
    }
    bool clo64 = true;
    {
        int lim = kS; if (lim > 128) lim = 128;
        for (int k = 1; k < lim; k += 2)
            if (closest[k] != 0) { clo64 = false; break; }
    }

    int c = closest[clo64 ? 2 * s : s];
    if (c < 0) c = 0;
    if (c >= kS) c = kS - 1;

    __shared__ int   sm_count;
    __shared__ int   sm_sym[kMaxMatch];
    __shared__ float sm_re[kA], sm_im[kA];

    if (tid == 0) sm_count = 0;
    __syncthreads();

    for (int p = tid; p < P; p += 64) {
        const int sc = est[est64 ? 4 * p + 2 : 2 * p + 1];
        if (sc == c) {
            const int sym = est[est64 ? 4 * p : 2 * p];
            if (sym >= 0 && sym < kT) {
                int slot = atomicAdd(&sm_count, 1);
                if (slot < kMaxMatch) sm_sym[slot] = sym;
            }
        }
    }
    __syncthreads();

    int count = sm_count;
    if (count > kMaxMatch) count = kMaxMatch;

    const int i  = tid >> 2;
    const int j0 = (tid & 3) * 4;

    float v0 = 0.f, v1 = 0.f, v2 = 0.f, v3 = 0.f;

    for (int m = 0; m < count; ++m) {
        const int sym = sm_sym[m];
        if (tid < kA) {
            const long off = (long)b * (kA * kT * kS) + (long)tid * (kT * kS)
                           + (long)sym * kS + c;
            sm_re[tid] = y_real[off];
            sm_im[tid] = y_imag[off];
        }
        __syncthreads();

        const float xr = sm_re[i], xi = sm_im[i];
        v0 += xr * sm_re[j0 + 0] + xi * sm_im[j0 + 0];
        v1 += xr * sm_re[j0 + 1] + xi * sm_im[j0 + 1];
        v2 += xr * sm_re[j0 + 2] + xi * sm_im[j0 + 2];
        v3 += xr * sm_re[j0 + 3] + xi * sm_im[j0 + 3];
        __syncthreads();
    }

    const float inv = 1.0f / (float)(count > 0 ? count : 1);
    const float4 v = make_float4(v0 * inv, v1 * inv, v2 * inv, v3 * inv);

    float4* __restrict__ out4 = (float4*)out;
    for (int t = 0; t < kT; ++t) {
        const long f4idx = ((long)(b * kT + t) * kS + s) * 64 + tid;
        if ((f4idx + 1) * 4 <= out_floats)
            out4[f4idx] = v;
    }
}

__global__ __launch_bounds__(128) void cov_cplx_kernel(
    const float* __restrict__ y_real,
    const float* __restrict__ y_imag,
    const int*   __restrict__ est,
    const int*   __restrict__ closest,
    float*       __restrict__ out,
    int P, long out_floats)
{
    const int blk = blockIdx.x;
    const int b   = blk >> 10;
    const int s   = blk & (kS - 1);
    const int tid = threadIdx.x;

    bool est64 = true;
    {
        int lim = 2 * P; if (lim > 128) lim = 128;
        for (int k = 1; k < lim; k += 2)
            if (est[k] != 0) { est64 = false; break; }
    }
    bool clo64 = true;
    {
        int lim = kS; if (lim > 128) lim = 128;
        for (int k = 1; k < lim; k += 2)
            if (closest[k] != 0) { clo64 = false; break; }
    }

    int c = closest[clo64 ? 2 * s : s];
    if (c < 0) c = 0;
    if (c >= kS) c = kS - 1;

    __shared__ int   sm_count;
    __shared__ int   sm_sym[kMaxMatch];
    __shared__ float sm_re[kA], sm_im[kA];

    if (tid == 0) sm_count = 0;
    __syncthreads();

    for (int p = tid; p < P; p += 128) {
        const int sc = est[est64 ? 4 * p + 2 : 2 * p + 1];
        if (sc == c) {
            const int sym = est[est64 ? 4 * p : 2 * p];
            if (sym >= 0 && sym < kT) {
                int slot = atomicAdd(&sm_count, 1);
                if (slot < kMaxMatch) sm_sym[slot] = sym;
            }
        }
    }
    __syncthreads();

    int count = sm_count;
    if (count > kMaxMatch) count = kMaxMatch;

    const int i  = tid >> 3;
    const int j0 = (tid & 7) * 2;

    float a0r = 0.f, a0i = 0.f, a1r = 0.f, a1i = 0.f;

    for (int m = 0; m < count; ++m) {
        const int sym = sm_sym[m];
        if (tid < kA) {
            const long off = (long)b * (kA * kT * kS) + (long)tid * (kT * kS)
                           + (long)sym * kS + c;
            sm_re[tid] = y_real[off];
            sm_im[tid] = y_imag[off];
        }
        __syncthreads();

        const float xr  = sm_re[i],      xi  = sm_im[i];
        const float y0r = sm_re[j0],     y0i = sm_im[j0];
        const float y1r = sm_re[j0 + 1], y1i = sm_im[j0 + 1];
        a0r += xr * y0r + xi * y0i;
        a0i += xi * y0r - xr * y0i;
        a1r += xr * y1r + xi * y1i;
        a1i += xi * y1r - xr * y1i;
        __syncthreads();
    }

    const float inv = 1.0f / (float)(count > 0 ? count : 1);
    const float4 v = make_float4(a0r * inv, a0i * inv, a1r * inv, a1i * inv);

    float4* __restrict__ out4 = (float4*)out;
    for (int t = 0; t < kT; ++t) {
        const long f4idx = ((long)(b * kT + t) * kS + s) * 128 + tid;
        if ((f4idx + 1) * 4 <= out_floats)
            out4[f4idx] = v;
    }
}

extern "C" void kernel_launch(void* const* d_in, const int* in_sizes, int n_in,
                              void* d_out, int out_size, void* d_ws, size_t ws_size,
                              hipStream_t stream) {
    const float* y_real  = (const float*)d_in[0];
    const float* y_imag  = (const float*)d_in[1];
    const int*   est     = (const int*)d_in[2];
    const int*   closest = (const int*)d_in[3];
    float*       out     = (float*)d_out;

    const int  P     = in_sizes[2] / 2;
    const long realN = (long)kB * kT * kS * kA * kA;          // 58,720,256
    const long wsNeed = (long)kB * kS * 128 * 16;             // 33,554,432 B

    dim3 grid(kB * kS);
    if ((long)out_size >= 2 * realN) {
        if (ws_size >= (size_t)wsNeed) {
            // fast path: compute once (33.5 MB) then stream-broadcast (470 MB)
            fvec4* ws4 = (fvec4*)d_ws;
            cov_compute_ws<<<grid, dim3(128), 0, stream>>>(
                y_real, y_imag, est, closest, ws4, P);
            cov_broadcast<<<dim3(kB * (kS / 8)), dim3(256), 0, stream>>>(
                ws4, (fvec4*)out, (long)out_size);
        } else {
            cov_cplx_kernel<<<grid, dim3(128), 0, stream>>>(
                y_real, y_imag, est, closest, out, P, (long)out_size);
        }
    } else {
        cov_real_kernel<<<grid, dim3(64), 0, stream>>>(
            y_real, y_imag, est, closest, out, P, (long)out_size);
    }
}

// Round 3
// 264.847 us; speedup vs baseline: 1.0074x; 1.0074x over previous
//
#include <hip/hip_runtime.h>

// Problem constants (from reference setup_inputs): B=16, R=1, A=16, T=14, S=1024
static constexpr int kB = 16;
static constexpr int kA = 16;
static constexpr int kT = 14;
static constexpr int kS = 1024;
static constexpr int kMaxMatch = 32;
static constexpr int kRows = 8;          // s-rows per block (fused kernel)

// native clang vector (required by __builtin_nontemporal_store)
typedef __attribute__((ext_vector_type(4))) float fvec4;

// y layout: (B, R=1, A, T, S) float32 contiguous.
// Output (complex path): (B, R=1, T, S, A, A) complex64 interleaved.
// Row layout per (b,t,s): 256 complex = 512 floats = 128 float4; float4 slot q
// holds complex elems (2q, 2q+1) = cov[i][j0], cov[i][j0+1] with
// i = q>>3, j0 = (q&7)*2.  (Verified mapping from the 262us session kernel.)

// ==========================================================================
// FUSED kernel: block = (b, 8 subcarriers), 256 threads (4 waves).
//   row  = tid>>5 (0..7) -> subcarrier s0+row, owned by a half-wave
//   lane = tid&31        -> q slots 4*lane .. 4*lane+3 of that row
// Phase 1: per-row est scan + up-to-2 gather/accumulate rounds (latency-bound
//          prologue, paid once per block; all 2048 blocks co-resident).
// Phase 2: stage 8x128 float4 in LDS, transpose-read, stream 14 x 16 KB
//          contiguous nontemporal stores (pure fill-like streaming).
// ==========================================================================
__global__ __launch_bounds__(256) void cov_fused(
    const float* __restrict__ y_real,
    const float* __restrict__ y_imag,
    const int*   __restrict__ est,      // (P,2): [sym, sc] int32 (sniffs int64 too)
    const int*   __restrict__ closest,  // (S,)  int32 (sniffs int64 too)
    fvec4*       __restrict__ out4,
    int P, long out_floats)
{
    const int b    = blockIdx.x >> 7;        // kS/kRows = 128 chunks per b
    const int s0   = (blockIdx.x & 127) << 3;
    const int tid  = threadIdx.x;
    const int row  = tid >> 5;               // 0..7
    const int lane = tid & 31;               // 0..31

    // layout sniff: int64 arrays of small values have all-zero odd words
    bool est64 = true;
    {
        int lim = 2 * P; if (lim > 128) lim = 128;
        for (int k = 1; k < lim; k += 2)
            if (est[k] != 0) { est64 = false; break; }
    }
    bool clo64 = true;
    {
        int lim = kS; if (lim > 128) lim = 128;
        for (int k = 1; k < lim; k += 2)
            if (closest[k] != 0) { clo64 = false; break; }
    }

    __shared__ int   sm_c[kRows];
    __shared__ int   sm_cnt[kRows];
    __shared__ int   sm_sym[kRows][kMaxMatch];
    __shared__ float sm_re[kRows][kA];
    __shared__ float sm_im[kRows][kA];
    __shared__ fvec4 sm_out[kRows * 128];    // 16 KB result stage

    if (tid < kRows) {
        const int s = s0 + tid;
        int c = closest[clo64 ? 2 * s : s];
        if (c < 0) c = 0;
        if (c >= kS) c = kS - 1;
        sm_c[tid]   = c;
        sm_cnt[tid] = 0;
    }
    __syncthreads();

    // per-row est scan: the row's 32 threads stride the table
    {
        const int c = sm_c[row];
        for (int p = lane; p < P; p += 32) {
            const int sc = est[est64 ? 4 * p + 2 : 2 * p + 1];
            if (sc == c) {
                const int sym = est[est64 ? 4 * p : 2 * p];
                if (sym >= 0 && sym < kT) {
                    int slot = atomicAdd(&sm_cnt[row], 1);
                    if (slot < kMaxMatch) sm_sym[row][slot] = sym;
                }
            }
        }
    }
    __syncthreads();

    int cnt = sm_cnt[row]; if (cnt > kMaxMatch) cnt = kMaxMatch;
    int mmax = 0;
    #pragma unroll
    for (int r = 0; r < kRows; ++r) {
        int cr = sm_cnt[r]; if (cr > kMaxMatch) cr = kMaxMatch;
        if (cr > mmax) mmax = cr;
    }

    float acc[16];
    #pragma unroll
    for (int k = 0; k < 16; ++k) acc[k] = 0.f;

    const int i = lane >> 1;                 // antenna row index for this thread

    for (int m = 0; m < mmax; ++m) {
        // cooperative gather: tid<128 load re[r][a], tid>=128 load im[r][a]
        {
            const int half = tid >> 7;
            const int r    = (tid >> 4) & 7;
            const int a    = tid & 15;
            int cr = sm_cnt[r]; if (cr > kMaxMatch) cr = kMaxMatch;
            if (m < cr) {
                const int sym = sm_sym[r][m];
                const long off = (long)b * (kA * kT * kS) + (long)a * (kT * kS)
                               + (long)sym * kS + sm_c[r];
                if (half == 0) sm_re[r][a] = y_real[off];
                else           sm_im[r][a] = y_imag[off];
            }
        }
        __syncthreads();

        if (m < cnt) {
            const float xr = sm_re[row][i], xi = sm_im[row][i];
            #pragma unroll
            for (int k = 0; k < 4; ++k) {
                const int q  = 4 * lane + k;
                const int j0 = (q & 7) * 2;
                const float y0r = sm_re[row][j0],     y0i = sm_im[row][j0];
                const float y1r = sm_re[row][j0 + 1], y1i = sm_im[row][j0 + 1];
                acc[4 * k + 0] += xr * y0r + xi * y0i;
                acc[4 * k + 1] += xi * y0r - xr * y0i;
                acc[4 * k + 2] += xr * y1r + xi * y1i;
                acc[4 * k + 3] += xi * y1r - xr * y1i;
            }
        }
        __syncthreads();
    }

    const float inv = 1.0f / (float)(cnt > 0 ? cnt : 1);
    #pragma unroll
    for (int k = 0; k < 4; ++k) {
        fvec4 v;
        v.x = acc[4 * k + 0] * inv;
        v.y = acc[4 * k + 1] * inv;
        v.z = acc[4 * k + 2] * inv;
        v.w = acc[4 * k + 3] * inv;
        sm_out[row * 128 + 4 * lane + k] = v;
    }
    __syncthreads();

    // transpose-read: thread tid owns chunk-linear float4 slots tid+256k
    const fvec4 r0 = sm_out[tid];
    const fvec4 r1 = sm_out[tid + 256];
    const fvec4 r2 = sm_out[tid + 512];
    const fvec4 r3 = sm_out[tid + 768];

    #pragma unroll
    for (int t = 0; t < kT; ++t) {
        const long base = ((long)((b * kT + t) << 10) + s0) * 128;
        // uniform fast-path check (scalar branch); guard: (idx+1)*4 <= out_floats
        if ((base + 1024) * 4 <= out_floats) {
            __builtin_nontemporal_store(r0, out4 + base + tid);
            __builtin_nontemporal_store(r1, out4 + base + tid + 256);
            __builtin_nontemporal_store(r2, out4 + base + tid + 512);
            __builtin_nontemporal_store(r3, out4 + base + tid + 768);
        } else {
            if ((base + tid + 1)       * 4 <= out_floats) out4[base + tid]       = r0;
            if ((base + tid + 256 + 1) * 4 <= out_floats) out4[base + tid + 256] = r1;
            if ((base + tid + 512 + 1) * 4 <= out_floats) out4[base + tid + 512] = r2;
            if ((base + tid + 768 + 1) * 4 <= out_floats) out4[base + tid + 768] = r3;
        }
    }
}

// ==========================================================================
// FALLBACK: real-output kernel (verbatim from verified session).
// ==========================================================================
__global__ __launch_bounds__(64) void cov_real_kernel(
    const float* __restrict__ y_real,
    const float* __restrict__ y_imag,
    const int*   __restrict__ est,
    const int*   __restrict__ closest,
    float*       __restrict__ out,
    int P, long out_floats)
{
    const int blk = blockIdx.x;
    const int b   = blk >> 10;
    const int s   = blk & (kS - 1);
    const int tid = threadIdx.x;

    bool est64 = true;
    {
        int lim = 2 * P; if (lim > 128) lim = 128;
        for (int k = 1; k < lim; k += 2)
            if (est[k] != 0) { est64 = false; break; }
    }
    bool clo64 = true;
    {
        int lim = kS; if (lim > 128) lim = 128;
        for (int k = 1; k < lim; k += 2)
            if (closest[k] != 0) { clo64 = false; break; }
    }

    int c = closest[clo64 ? 2 * s : s];
    if (c < 0) c = 0;
    if (c >= kS) c = kS - 1;

    __shared__ int   sm_count;
    __shared__ int   sm_sym[kMaxMatch];
    __shared__ float sm_re[kA], sm_im[kA];

    if (tid == 0) sm_count = 0;
    __syncthreads();

    for (int p = tid; p < P; p += 64) {
        const int sc = est[est64 ? 4 * p + 2 : 2 * p + 1];
        if (sc == c) {
            const int sym = est[est64 ? 4 * p : 2 * p];
            if (sym >= 0 && sym < kT) {
                int slot = atomicAdd(&sm_count, 1);
                if (slot < kMaxMatch) sm_sym[slot] = sym;
            }
        }
    }
    __syncthreads();

    int count = sm_count;
    if (count > kMaxMatch) count = kMaxMatch;

    const int i  = tid >> 2;
    const int j0 = (tid & 3) * 4;

    float v0 = 0.f, v1 = 0.f, v2 = 0.f, v3 = 0.f;

    for (int m = 0; m < count; ++m) {
        const int sym = sm_sym[m];
        if (tid < kA) {
            const long off = (long)b * (kA * kT * kS) + (long)tid * (kT * kS)
                           + (long)sym * kS + c;
            sm_re[tid] = y_real[off];
            sm_im[tid] = y_imag[off];
        }
        __syncthreads();

        const float xr = sm_re[i], xi = sm_im[i];
        v0 += xr * sm_re[j0 + 0] + xi * sm_im[j0 + 0];
        v1 += xr * sm_re[j0 + 1] + xi * sm_im[j0 + 1];
        v2 += xr * sm_re[j0 + 2] + xi * sm_im[j0 + 2];
        v3 += xr * sm_re[j0 + 3] + xi * sm_im[j0 + 3];
        __syncthreads();
    }

    const float inv = 1.0f / (float)(count > 0 ? count : 1);
    const float4 v = make_float4(v0 * inv, v1 * inv, v2 * inv, v3 * inv);

    float4* __restrict__ out4 = (float4*)out;
    for (int t = 0; t < kT; ++t) {
        const long f4idx = ((long)(b * kT + t) * kS + s) * 64 + tid;
        if ((f4idx + 1) * 4 <= out_floats)
            out4[f4idx] = v;
    }
}

extern "C" void kernel_launch(void* const* d_in, const int* in_sizes, int n_in,
                              void* d_out, int out_size, void* d_ws, size_t ws_size,
                              hipStream_t stream) {
    const float* y_real  = (const float*)d_in[0];
    const float* y_imag  = (const float*)d_in[1];
    const int*   est     = (const int*)d_in[2];
    const int*   closest = (const int*)d_in[3];
    float*       out     = (float*)d_out;

    const int  P     = in_sizes[2] / 2;
    const long realN = (long)kB * kT * kS * kA * kA;          // 58,720,256

    if ((long)out_size >= 2 * realN) {
        // complex path: fused compute+broadcast, 2048 fully-resident blocks
        cov_fused<<<dim3(kB * (kS / kRows)), dim3(256), 0, stream>>>(
            y_real, y_imag, est, closest, (fvec4*)out, P, (long)out_size);
    } else {
        dim3 grid(kB * kS);
        cov_real_kernel<<<grid, dim3(64), 0, stream>>>(
            y_real, y_imag, est, closest, out, P, (long)out_size);
    }
}

// Round 4
// 259.522 us; speedup vs baseline: 1.0281x; 1.0205x over previous
//
#include <hip/hip_runtime.h>

// Problem constants (from reference setup_inputs): B=16, R=1, A=16, T=14, S=1024
static constexpr int kB = 16;
static constexpr int kA = 16;
static constexpr int kT = 14;
static constexpr int kS = 1024;
static constexpr int kMaxMatch = 32;

// native clang vector (required by __builtin_nontemporal_store)
typedef __attribute__((ext_vector_type(4))) float fvec4;

// y layout: (B, R=1, A, T, S) float32 contiguous.
// Output (complex path): (B, R=1, T, S, A, A) complex64 interleaved.
// Row layout per (b,t,s): 256 complex = 512 floats = 128 float4; float4 slot q
// holds complex elems (2q, 2q+1) = cov[i][j0], cov[i][j0+1] with
// i = q>>3, j0 = (q&7)*2.  (Verified mapping from the 262us session kernel.)

// ws int layout:
//   wsi[0      .. 1023]                : decoded+clamped closest[s]
//   wsi[1024   .. 2047]                : per-subcarrier valid-match count
//   wsi[2048   .. 2048+1024*32-1]      : per-subcarrier match syms (first 32)
static constexpr long kWsInts = 2048 + (long)kS * kMaxMatch;   // 34,816 ints

// ==========================================================================
// Kernel M: build per-subcarrier metadata. ONE block, 1024 threads.
// Replaces the per-block est-table scan (was redundant 2048-16384x).
// ==========================================================================
__global__ __launch_bounds__(1024) void build_meta(
    const int* __restrict__ est,      // (P,2): [sym, sc] int32 (sniffs int64 too)
    const int* __restrict__ closest,  // (S,)  int32 (sniffs int64 too)
    int*       __restrict__ wsi,
    int P)
{
    const int tid = threadIdx.x;

    // layout sniff: int64 arrays of small values have all-zero odd words
    bool est64 = true;
    {
        int lim = 2 * P; if (lim > 128) lim = 128;
        for (int k = 1; k < lim; k += 2)
            if (est[k] != 0) { est64 = false; break; }
    }
    bool clo64 = true;
    {
        int lim = kS; if (lim > 128) lim = 128;
        for (int k = 1; k < lim; k += 2)
            if (closest[k] != 0) { clo64 = false; break; }
    }

    if (tid < kS) {
        int c = closest[clo64 ? 2 * tid : tid];
        if (c < 0) c = 0;
        if (c >= kS) c = kS - 1;
        wsi[tid]        = c;   // decoded closest
        wsi[kS + tid]   = 0;   // zero counts
    }
    __syncthreads();

    for (int p = tid; p < P; p += 1024) {
        const int sc = est[est64 ? 4 * p + 2 : 2 * p + 1];
        if (sc >= 0 && sc < kS) {
            const int sym = est[est64 ? 4 * p : 2 * p];
            if (sym >= 0 && sym < kT) {
                const int slot = atomicAdd(&wsi[kS + sc], 1);
                if (slot < kMaxMatch)
                    wsi[2 * kS + sc * kMaxMatch + slot] = sym;
            }
        }
    }
}

// ==========================================================================
// Kernel C: linear-sweep compute+write.
// Block = one contiguous 64 KB output panel: (b, t, 32 subcarriers).
// blk = (b*kT + t)*32 + scChunk  ->  panel float4 base = blk*4096.
// Grid covers the output buffer LINEARLY in blockIdx order (like the fill).
// 256 threads: thread owns 16 float4 accumulators (panel slots tid+256k).
// ==========================================================================
__global__ __launch_bounds__(256) void cov_linear(
    const float* __restrict__ y_real,
    const float* __restrict__ y_imag,
    const int*   __restrict__ wsi,
    fvec4*       __restrict__ out4,
    long out_floats)
{
    const int blk     = blockIdx.x;            // (b*14+t)*32 + scChunk
    const int scChunk = blk & 31;
    const int bt      = blk >> 5;              // b*14 + t
    const int b       = bt / kT;
    const int s0      = scChunk * 32;
    const int tid     = threadIdx.x;

    __shared__ int   sm_c[32];
    __shared__ int   sm_cnt[32];
    __shared__ int   sm_sym[32][2];            // first 2 syms inline (common case)
    __shared__ float sm_re[32][kA];
    __shared__ float sm_im[32][kA];

    if (tid < 32) {
        const int c = wsi[s0 + tid];
        int cnt = wsi[kS + c];
        if (cnt > kMaxMatch) cnt = kMaxMatch;
        sm_c[tid]   = c;
        sm_cnt[tid] = cnt;
        sm_sym[tid][0] = (cnt > 0) ? wsi[2 * kS + c * kMaxMatch + 0] : 0;
        sm_sym[tid][1] = (cnt > 1) ? wsi[2 * kS + c * kMaxMatch + 1] : 0;
    }
    __syncthreads();

    int mmax = 0;
    #pragma unroll 8
    for (int r = 0; r < 32; ++r) {
        const int cr = sm_cnt[r];
        if (cr > mmax) mmax = cr;
    }

    fvec4 acc[16];
    #pragma unroll
    for (int k = 0; k < 16; ++k) acc[k] = (fvec4)0.f;

    const long bbase = (long)b * (kA * kT * kS);

    for (int m = 0; m < mmax; ++m) {
        // cooperative gather: 1024 floats (32 rows x 16 ants x {re,im})
        #pragma unroll
        for (int k = 0; k < 4; ++k) {
            const int idx  = tid + 256 * k;
            const int half = idx >> 9;         // 0 = re, 1 = im
            const int r    = (idx >> 4) & 31;
            const int a    = idx & 15;
            if (m < sm_cnt[r]) {
                const int sym = (m < 2) ? sm_sym[r][m]
                                        : wsi[2 * kS + sm_c[r] * kMaxMatch + m];
                const long off = bbase + (long)a * (kT * kS) + (long)sym * kS + sm_c[r];
                if (half == 0) sm_re[r][a] = y_real[off];
                else           sm_im[r][a] = y_imag[off];
            }
        }
        __syncthreads();

        #pragma unroll
        for (int k = 0; k < 16; ++k) {
            const int idx = tid + 256 * k;
            const int r   = idx >> 7;          // panel row (local subcarrier)
            const int q   = idx & 127;
            if (m < sm_cnt[r]) {
                const int i  = q >> 3;
                const int j0 = (q & 7) * 2;
                const float xr  = sm_re[r][i],      xi  = sm_im[r][i];
                const float y0r = sm_re[r][j0],     y0i = sm_im[r][j0];
                const float y1r = sm_re[r][j0 + 1], y1i = sm_im[r][j0 + 1];
                acc[k].x += xr * y0r + xi * y0i;
                acc[k].y += xi * y0r - xr * y0i;
                acc[k].z += xr * y1r + xi * y1i;
                acc[k].w += xi * y1r - xr * y1i;
            }
        }
        __syncthreads();
    }

    // scale + linear panel store: block writes [blk*4096, blk*4096+4096) float4
    const long base4 = (long)blk * 4096;
    if ((base4 + 4096) * 4 <= out_floats) {
        #pragma unroll
        for (int k = 0; k < 16; ++k) {
            const int idx = tid + 256 * k;
            const int r   = idx >> 7;
            const int cr  = sm_cnt[r];
            const float inv = 1.0f / (float)(cr > 0 ? cr : 1);
            fvec4 v = acc[k];
            v.x *= inv; v.y *= inv; v.z *= inv; v.w *= inv;
            __builtin_nontemporal_store(v, out4 + base4 + idx);
        }
    } else {
        #pragma unroll
        for (int k = 0; k < 16; ++k) {
            const int idx = tid + 256 * k;
            const int r   = idx >> 7;
            const int cr  = sm_cnt[r];
            const float inv = 1.0f / (float)(cr > 0 ? cr : 1);
            fvec4 v = acc[k];
            v.x *= inv; v.y *= inv; v.z *= inv; v.w *= inv;
            if ((base4 + idx + 1) * 4 <= out_floats)
                out4[base4 + idx] = v;
        }
    }
}

// ==========================================================================
// FALLBACK kernels (verbatim from verified session) — used if ws too small
// or the real-output branch is taken.
// ==========================================================================
__global__ __launch_bounds__(64) void cov_real_kernel(
    const float* __restrict__ y_real,
    const float* __restrict__ y_imag,
    const int*   __restrict__ est,
    const int*   __restrict__ closest,
    float*       __restrict__ out,
    int P, long out_floats)
{
    const int blk = blockIdx.x;
    const int b   = blk >> 10;
    const int s   = blk & (kS - 1);
    const int tid = threadIdx.x;

    bool est64 = true;
    {
        int lim = 2 * P; if (lim > 128) lim = 128;
        for (int k = 1; k < lim; k += 2)
            if (est[k] != 0) { est64 = false; break; }
    }
    bool clo64 = true;
    {
        int lim = kS; if (lim > 128) lim = 128;
        for (int k = 1; k < lim; k += 2)
            if (closest[k] != 0) { clo64 = false; break; }
    }

    int c = closest[clo64 ? 2 * s : s];
    if (c < 0) c = 0;
    if (c >= kS) c = kS - 1;

    __shared__ int   sm_count;
    __shared__ int   sm_sym[kMaxMatch];
    __shared__ float sm_re[kA], sm_im[kA];

    if (tid == 0) sm_count = 0;
    __syncthreads();

    for (int p = tid; p < P; p += 64) {
        const int sc = est[est64 ? 4 * p + 2 : 2 * p + 1];
        if (sc == c) {
            const int sym = est[est64 ? 4 * p : 2 * p];
            if (sym >= 0 && sym < kT) {
                int slot = atomicAdd(&sm_count, 1);
                if (slot < kMaxMatch) sm_sym[slot] = sym;
            }
        }
    }
    __syncthreads();

    int count = sm_count;
    if (count > kMaxMatch) count = kMaxMatch;

    const int i  = tid >> 2;
    const int j0 = (tid & 3) * 4;

    float v0 = 0.f, v1 = 0.f, v2 = 0.f, v3 = 0.f;

    for (int m = 0; m < count; ++m) {
        const int sym = sm_sym[m];
        if (tid < kA) {
            const long off = (long)b * (kA * kT * kS) + (long)tid * (kT * kS)
                           + (long)sym * kS + c;
            sm_re[tid] = y_real[off];
            sm_im[tid] = y_imag[off];
        }
        __syncthreads();

        const float xr = sm_re[i], xi = sm_im[i];
        v0 += xr * sm_re[j0 + 0] + xi * sm_im[j0 + 0];
        v1 += xr * sm_re[j0 + 1] + xi * sm_im[j0 + 1];
        v2 += xr * sm_re[j0 + 2] + xi * sm_im[j0 + 2];
        v3 += xr * sm_re[j0 + 3] + xi * sm_im[j0 + 3];
        __syncthreads();
    }

    const float inv = 1.0f / (float)(count > 0 ? count : 1);
    const float4 v = make_float4(v0 * inv, v1 * inv, v2 * inv, v3 * inv);

    float4* __restrict__ out4 = (float4*)out;
    for (int t = 0; t < kT; ++t) {
        const long f4idx = ((long)(b * kT + t) * kS + s) * 64 + tid;
        if ((f4idx + 1) * 4 <= out_floats)
            out4[f4idx] = v;
    }
}

__global__ __launch_bounds__(128) void cov_cplx_kernel(
    const float* __restrict__ y_real,
    const float* __restrict__ y_imag,
    const int*   __restrict__ est,
    const int*   __restrict__ closest,
    float*       __restrict__ out,
    int P, long out_floats)
{
    const int blk = blockIdx.x;
    const int b   = blk >> 10;
    const int s   = blk & (kS - 1);
    const int tid = threadIdx.x;

    bool est64 = true;
    {
        int lim = 2 * P; if (lim > 128) lim = 128;
        for (int k = 1; k < lim; k += 2)
            if (est[k] != 0) { est64 = false; break; }
    }
    bool clo64 = true;
    {
        int lim = kS; if (lim > 128) lim = 128;
        for (int k = 1; k < lim; k += 2)
            if (closest[k] != 0) { clo64 = false; break; }
    }

    int c = closest[clo64 ? 2 * s : s];
    if (c < 0) c = 0;
    if (c >= kS) c = kS - 1;

    __shared__ int   sm_count;
    __shared__ int   sm_sym[kMaxMatch];
    __shared__ float sm_re[kA], sm_im[kA];

    if (tid == 0) sm_count = 0;
    __syncthreads();

    for (int p = tid; p < P; p += 128) {
        const int sc = est[est64 ? 4 * p + 2 : 2 * p + 1];
        if (sc == c) {
            const int sym = est[est64 ? 4 * p : 2 * p];
            if (sym >= 0 && sym < kT) {
                int slot = atomicAdd(&sm_count, 1);
                if (slot < kMaxMatch) sm_sym[slot] = sym;
            }
        }
    }
    __syncthreads();

    int count = sm_count;
    if (count > kMaxMatch) count = kMaxMatch;

    const int i  = tid >> 3;
    const int j0 = (tid & 7) * 2;

    float a0r = 0.f, a0i = 0.f, a1r = 0.f, a1i = 0.f;

    for (int m = 0; m < count; ++m) {
        const int sym = sm_sym[m];
        if (tid < kA) {
            const long off = (long)b * (kA * kT * kS) + (long)tid * (kT * kS)
                           + (long)sym * kS + c;
            sm_re[tid] = y_real[off];
            sm_im[tid] = y_imag[off];
        }
        __syncthreads();

        const float xr  = sm_re[i],      xi  = sm_im[i];
        const float y0r = sm_re[j0],     y0i = sm_im[j0];
        const float y1r = sm_re[j0 + 1], y1i = sm_im[j0 + 1];
        a0r += xr * y0r + xi * y0i;
        a0i += xi * y0r - xr * y0i;
        a1r += xr * y1r + xi * y1i;
        a1i += xi * y1r - xr * y1i;
        __syncthreads();
    }

    const float inv = 1.0f / (float)(count > 0 ? count : 1);
    const float4 v = make_float4(a0r * inv, a0i * inv, a1r * inv, a1i * inv);

    float4* __restrict__ out4 = (float4*)out;
    for (int t = 0; t < kT; ++t) {
        const long f4idx = ((long)(b * kT + t) * kS + s) * 128 + tid;
        if ((f4idx + 1) * 4 <= out_floats)
            out4[f4idx] = v;
    }
}

extern "C" void kernel_launch(void* const* d_in, const int* in_sizes, int n_in,
                              void* d_out, int out_size, void* d_ws, size_t ws_size,
                              hipStream_t stream) {
    const float* y_real  = (const float*)d_in[0];
    const float* y_imag  = (const float*)d_in[1];
    const int*   est     = (const int*)d_in[2];
    const int*   closest = (const int*)d_in[3];
    float*       out     = (float*)d_out;

    const int  P      = in_sizes[2] / 2;
    const long realN  = (long)kB * kT * kS * kA * kA;         // 58,720,256
    const long wsNeed = kWsInts * 4;                          // 139,264 B

    if ((long)out_size >= 2 * realN) {
        if (ws_size >= (size_t)wsNeed) {
            // fast path: metadata once, then linear-sweep compute+write
            int* wsi = (int*)d_ws;
            build_meta<<<dim3(1), dim3(1024), 0, stream>>>(est, closest, wsi, P);
            cov_linear<<<dim3(kB * kT * 32), dim3(256), 0, stream>>>(
                y_real, y_imag, wsi, (fvec4*)out, (long)out_size);
        } else {
            dim3 grid(kB * kS);
            cov_cplx_kernel<<<grid, dim3(128), 0, stream>>>(
                y_real, y_imag, est, closest, out, P, (long)out_size);
        }
    } else {
        dim3 grid(kB * kS);
        cov_real_kernel<<<grid, dim3(64), 0, stream>>>(
            y_real, y_imag, est, closest, out, P, (long)out_size);
    }
}